// Round 9
// baseline (174.853 us; speedup 1.0000x reference)
//
#include <hip/hip_runtime.h>
#include <math.h>

// Problem constants
#define XD 128
#define YD 128
#define ZD 8
#define ED 64
#define KD 3
#define NITER 3
#define FHD 96
#define FWD 320
#define HALF_W 640.0f
#define HALF_H 192.0f

#define ASTRIDE 80   // shorts per A-tile row (160 B: 16B-aligned; ~zero conflicts R3/R4/R7)
#define DSTR 28      // floats per logit-tile row
#define HSTR 68      // floats per H-tile row

// Single per-wave LDS UNION region (serial wave-private lifetimes, in-order DS):
//   Ab bf16 A-tile (16*80*2 = 2560 B)  ->  Db logits (16*28*4 = 1792 B)
//   -> Ab (stage 2) -> Hb (16*68*4 = 4352 B)
#define WAVE_LDS 4352

typedef __attribute__((ext_vector_type(8))) short short8;
typedef __attribute__((ext_vector_type(4))) float f32x4;
typedef float          __attribute__((may_alias)) fal;
typedef unsigned short __attribute__((may_alias)) usal;

__device__ __forceinline__ unsigned short f2bf(float f) {
    unsigned u = __float_as_uint(f);
    u += 0x7fff + ((u >> 16) & 1);
    return (unsigned short)(u >> 16);
}

__device__ __forceinline__ float bf2f(unsigned short u) {
    return __int_as_float(((int)u) << 16);
}

__device__ __forceinline__ float rdlane_f(float v, int s) {
    return __int_as_float(__builtin_amdgcn_readlane(__float_as_int(v), s));
}

// sum over each 16-lane DPP row via row_ror 1,2,4,8 (pure VALU, no DS pipe)
__device__ __forceinline__ float rowsum16(float v) {
    v += __int_as_float(__builtin_amdgcn_update_dpp(0, __float_as_int(v), 0x121, 0xf, 0xf, true));
    v += __int_as_float(__builtin_amdgcn_update_dpp(0, __float_as_int(v), 0x122, 0xf, 0xf, true));
    v += __int_as_float(__builtin_amdgcn_update_dpp(0, __float_as_int(v), 0x124, 0xf, 0xf, true));
    v += __int_as_float(__builtin_amdgcn_update_dpp(0, __float_as_int(v), 0x128, 0xf, 0xf, true));
    return v;
}

// -------- prep: img CHW->HWC bf16 transpose (blocks 0..479) + weight frags + pad --
__global__ __launch_bounds__(256) void k_prep(const float* __restrict__ img,
                                              unsigned short* __restrict__ outHWC,
                                              const float* __restrict__ W_off,
                                              const float* __restrict__ W_w,
                                              const float* __restrict__ W_l,
                                              unsigned short* __restrict__ W9f,
                                              unsigned short* __restrict__ Wlf) {
    if (blockIdx.x < (FHD * FWD) / 64) {
        __shared__ float tile[64][65];
        const int hw0 = blockIdx.x * 64;
        const int lane = threadIdx.x & 63;
        const int r = threadIdx.x >> 6;
#pragma unroll
        for (int i = 0; i < 16; ++i) {
            int e = r + 4 * i;
            tile[e][lane] = img[e * (FHD * FWD) + hw0 + lane];
        }
        __syncthreads();
#pragma unroll
        for (int i = 0; i < 16; ++i) {
            int row = r + 4 * i;
            outHWC[(hw0 + row) * 64 + lane] = f2bf(tile[lane][row]);
        }
    } else {
        int idx = (blockIdx.x - (FHD * FWD) / 64) * 256 + threadIdx.x;
        if (idx < 3 * 4 * 2 * 64) {
            int lane = idx & 63, s = (idx >> 6) & 1, t = (idx >> 7) & 3, i = idx >> 9;
            int n = t * 16 + (lane & 15), quad = lane >> 4;
#pragma unroll
            for (int jj = 0; jj < 8; ++jj) {
                int ep = s * 32 + quad * 8 + jj;
                Wlf[idx * 8 + jj] = f2bf(W_l[(i * ED + ep) * ED + n]);
            }
        } else if (idx < 3 * 4 * 2 * 64 + 3 * 2 * 64) {
            int k = idx - 3 * 4 * 2 * 64;
            int lane = k & 63, s = (k >> 6) & 1, i = k >> 7;
            int n = lane & 15, quad = lane >> 4;
#pragma unroll
            for (int jj = 0; jj < 8; ++jj) {
                int ep = s * 32 + quad * 8 + jj;
                float v = 0.0f;
                if (n < 6) v = W_off[(i * ED + ep) * 6 + n];
                else if (n < 9) v = W_w[(i * ED + ep) * 3 + (n - 6)];
                W9f[k * 8 + jj] = f2bf(v);
            }
        } else if (idx < 3 * 4 * 2 * 64 + 3 * 2 * 64 + 64) {
            // zero the 128 B guard row past imgHWC (read by +1-col loads w/ weight 0)
            outHWC[FHD * FWD * 64 + (idx - (3 * 4 * 2 * 64 + 3 * 2 * 64))] = 0;
        }
    }
}

// -------- main fused kernel: one wave per TWO (x,y) points, 16 MFMA rows --------
__global__ __launch_bounds__(256, 4) void k_main(
    const float* __restrict__ Tv,     // (3,4)
    const float* __restrict__ intr,   // (3,3)
    const unsigned short* __restrict__ imgHWC, // (FH*FW, E) bf16 + guard
    const float* __restrict__ bev_in, // (X,Y,Z,E)
    const unsigned short* __restrict__ W9f,
    const unsigned short* __restrict__ Wlf,
    const float* __restrict__ b_off,  // (I,6)
    const float* __restrict__ s_off,  // (I,)
    const float* __restrict__ b_w,    // (I,3)
    const float* __restrict__ b_l,    // (I,E)
    const float* __restrict__ ln_g,   // (I,E)
    const float* __restrict__ ln_b,   // (I,E)
    float* __restrict__ tmp)          // (Y*X, E)
{
    __shared__ __align__(16) char smem[4 * WAVE_LDS];

    const int lane = threadIdx.x & 63;
    const int wv = threadIdx.x >> 6;
    const int wid2 = __builtin_amdgcn_readfirstlane(blockIdx.x * 4 + wv);
    const int m16 = lane & 15;
    const int quad = lane >> 4;

    char* base = smem + wv * WAVE_LDS;
    usal* Ab = (usal*)base;
    fal*  Db = (fal*)base;
    fal*  Hb = (fal*)base;

    const char* imgB = (const char*)imgHWC;

    // T = intr @ Tv (3x4), uniform
    float T[12];
#pragma unroll
    for (int r = 0; r < 3; ++r)
#pragma unroll
        for (int c = 0; c < 4; ++c)
            T[r * 4 + c] = intr[r * 3 + 0] * Tv[0 * 4 + c] +
                           intr[r * 3 + 1] * Tv[1 * 4 + c] +
                           intr[r * 3 + 2] * Tv[2 * 4 + c];

    // per-lane descriptor identity: lane s handles sample (m = s/3, k = s%3), s<48
    const int sm = min(lane / 3, 15);
    const int sk = lane - (lane / 3) * 3;

    // per-lane projected base coords for row sm
    float cxd, cyd;
    {
        int p = sm >> 3, z = sm & 7;
        int q = 2 * wid2 + p;
        int x = q & (XD - 1);
        int y = q >> 7;
        float gx = x * 0.8f;
        float gy = 51.2f - y * 0.8f;
        float gz = z * 0.5f - 2.5f;
        float p0 = T[0] * gx + T[1] * gy + T[2] * gz + T[3];
        float p1 = T[4] * gx + T[5] * gy + T[6] * gz + T[7];
        float p2 = T[8] * gx + T[9] * gy + T[10] * gz + T[11];
        cxd = (p0 / p2) / HALF_W - 1.0f;
        cyd = (p1 / p2) / HALF_H - 1.0f;
    }

    // two points per wave; rows m = p*8 + z
    float bev[16];
#pragma unroll
    for (int p = 0; p < 2; ++p) {
        int q = 2 * wid2 + p;
        int x = q & (XD - 1);
        int y = q >> 7;
        int pbase = (((x << 7) | y) << 9);
#pragma unroll
        for (int z = 0; z < ZD; ++z)
            bev[p * 8 + z] = bev_in[pbase + z * ED + lane];
    }

    for (int i = 0; i < NITER; ++i) {
        // ---- stage 1: logits = bev(16x64) @ W9(64x9) via 2 MFMAs ----
#pragma unroll
        for (int m = 0; m < 16; ++m) Ab[m * ASTRIDE + lane] = f2bf(bev[m]);

        short8 wb0 = *(const short8*)(W9f + ((i * 2 + 0) * 64 + lane) * 8);
        short8 wb1 = *(const short8*)(W9f + ((i * 2 + 1) * 64 + lane) * 8);
        short8 a0 = *(const short8*)(Ab + m16 * ASTRIDE + quad * 8);
        short8 a1 = *(const short8*)(Ab + m16 * ASTRIDE + 32 + quad * 8);
        f32x4 dlog = {0.0f, 0.0f, 0.0f, 0.0f};
        dlog = __builtin_amdgcn_mfma_f32_16x16x32_bf16(a0, wb0, dlog, 0, 0, 0);
        dlog = __builtin_amdgcn_mfma_f32_16x16x32_bf16(a1, wb1, dlog, 0, 0, 0);
        // D-layout -> Db (overwrites A-tile region; A already consumed)
#pragma unroll
        for (int r = 0; r < 4; ++r) Db[(quad * 4 + r) * DSTR + m16] = dlog[r];

        const float so = s_off[i];
        const float bo0 = b_off[i * 6 + 0], bo1 = b_off[i * 6 + 1], bo2 = b_off[i * 6 + 2];
        const float bo3 = b_off[i * 6 + 3], bo4 = b_off[i * 6 + 4], bo5 = b_off[i * 6 + 5];
        const float bw0 = b_w[i * 3 + 0], bw1 = b_w[i * 3 + 1], bw2 = b_w[i * 3 + 2];

        // ---- lane-parallel sample descriptors, kept in REGISTERS ----
        int rowA, rowB;
        float dw0, dw1, dw2, dw3;
        {
            const fal* Dm = Db + sm * DSTR;
            f32x4 qa = *(const f32x4*)(Dm);       // logits 0..3
            f32x4 qb = *(const f32x4*)(Dm + 4);   // logits 4..7
            float l8 = Dm[8];

            float ox0 = (qa[0] + bo0) * so, oy0 = (qa[1] + bo1) * so;
            float ox1 = (qa[2] + bo2) * so, oy1 = (qa[3] + bo3) * so;
            float ox2 = (qb[0] + bo4) * so, oy2 = (qb[1] + bo5) * so;
            float l0 = qb[2] + bw0, l1 = qb[3] + bw1, l2 = l8 + bw2;
            float mx = fmaxf(fmaxf(l0, l1), l2);
            float e0 = __expf(l0 - mx), e1 = __expf(l1 - mx), e2 = __expf(l2 - mx);
            float inv = 1.0f / (e0 + e1 + e2);
            float wk0 = e0 * inv, wk1 = e1 * inv, wk2 = e2 * inv;

            float wkk = (sk == 0) ? wk0 : ((sk == 1) ? wk1 : wk2);
            float ox  = (sk == 0) ? ox0 : ((sk == 1) ? ox1 : ox2);
            float oy  = (sk == 0) ? oy0 : ((sk == 1) ? oy1 : oy2);

            float gxx = cxd + ox, gyy = cyd + oy;
            float px = ((gxx + 1.0f) * (float)FWD - 1.0f) * 0.5f;
            float py = ((gyy + 1.0f) * (float)FHD - 1.0f) * 0.5f;
            float x0f = floorf(px), y0f = floorf(py);
            float fx = px - x0f, fy = py - y0f;
            int ix0 = (int)x0f, iy0 = (int)y0f;
            int iy1 = iy0 + 1;

            int cb = min(max(ix0, 0), FWD - 1);
            float wA = (ix0 >= 0 && ix0 < FWD) ? (1.0f - fx)
                                               : ((ix0 == -1) ? fx : 0.0f);
            float wB = (ix0 >= 0 && ix0 + 1 < FWD) ? fx : 0.0f;

            int rb0 = min(max(iy0, 0), FHD - 1);
            int rb1 = min(max(iy1, 0), FHD - 1);
            float wy0v = (iy0 >= 0 && iy0 < FHD) ? (1.0f - fy) : 0.0f;
            float wy1v = (iy1 >= 0 && iy1 < FHD) ? fy : 0.0f;

            rowA = rb0 * FWD + cb;
            rowB = rb1 * FWD + cb;
            dw0 = wkk * wA * wy0v;
            dw1 = wkk * wB * wy0v;
            dw2 = wkk * wA * wy1v;
            dw3 = wkk * wB * wy1v;
        }

        // ---- sampling: v_readlane -> SGPR bases/weights; bf16 128 B wave-loads ----
        float b2[16];
#pragma unroll
        for (int m = 0; m < 16; ++m) {
            float featA = 0.0f, featB = 0.0f;   // two 6-deep chains instead of one 12
#pragma unroll
            for (int k = 0; k < KD; ++k) {
                const int s = m * 3 + k;
                int offA = __builtin_amdgcn_readlane(rowA, s);
                int offB = __builtin_amdgcn_readlane(rowB, s);
                float w0 = rdlane_f(dw0, s);
                float w1 = rdlane_f(dw1, s);
                float w2 = rdlane_f(dw2, s);
                float w3 = rdlane_f(dw3, s);
                const usal* pA = (const usal*)(imgB + ((size_t)(unsigned)offA << 7)) + lane;
                const usal* pB = (const usal*)(imgB + ((size_t)(unsigned)offB << 7)) + lane;
                float vA0 = bf2f(pA[0]), vA1 = bf2f(pA[64]);  // +128 B (next column)
                float vB0 = bf2f(pB[0]), vB1 = bf2f(pB[64]);
                featA = fmaf(w0, vA0, featA);
                featA = fmaf(w1, vA1, featA);
                featB = fmaf(w2, vB0, featB);
                featB = fmaf(w3, vB1, featB);
            }
            b2[m] = bev[m] + (featA + featB);  // bev_mid
        }

        // ---- stage 2: h = bev_mid(16x64) @ W_l + b_l via 8 MFMAs ----
#pragma unroll
        for (int m = 0; m < 16; ++m) Ab[m * ASTRIDE + lane] = f2bf(b2[m]);
        short8 a0b = *(const short8*)(Ab + m16 * ASTRIDE + quad * 8);
        short8 a1b = *(const short8*)(Ab + m16 * ASTRIDE + 32 + quad * 8);
        f32x4 accs[4];
#pragma unroll
        for (int t = 0; t < 4; ++t) {
            float bb = b_l[i * ED + t * 16 + m16];
            f32x4 acc = {bb, bb, bb, bb};
            short8 w0 = *(const short8*)(Wlf + (((i * 4 + t) * 2 + 0) * 64 + lane) * 8);
            short8 w1 = *(const short8*)(Wlf + (((i * 4 + t) * 2 + 1) * 64 + lane) * 8);
            acc = __builtin_amdgcn_mfma_f32_16x16x32_bf16(a0b, w0, acc, 0, 0, 0);
            acc = __builtin_amdgcn_mfma_f32_16x16x32_bf16(a1b, w1, acc, 0, 0, 0);
            accs[t] = acc;
        }

        // ---- LayerNorm in D-layout: rows quad*4+r, cols t*16+m16 (DPP row-sums) ----
        float s1[4], s2[4];
#pragma unroll
        for (int r = 0; r < 4; ++r) {
            s1[r] = accs[0][r] + accs[1][r] + accs[2][r] + accs[3][r];
            s2[r] = accs[0][r] * accs[0][r];
            s2[r] = fmaf(accs[1][r], accs[1][r], s2[r]);
            s2[r] = fmaf(accs[2][r], accs[2][r], s2[r]);
            s2[r] = fmaf(accs[3][r], accs[3][r], s2[r]);
            s1[r] = rowsum16(s1[r]);
            s2[r] = rowsum16(s2[r]);
        }
        float gt[4], bt[4];
#pragma unroll
        for (int t = 0; t < 4; ++t) {
            gt[t] = ln_g[i * ED + t * 16 + m16];
            bt[t] = ln_b[i * ED + t * 16 + m16];
        }
#pragma unroll
        for (int r = 0; r < 4; ++r) {
            float mu = s1[r] * (1.0f / 64.0f);
            float var = fmaxf(s2[r] * (1.0f / 64.0f) - mu * mu, 0.0f);
            float rs = rsqrtf(var + 1e-5f);
            int row = quad * 4 + r;
#pragma unroll
            for (int t = 0; t < 4; ++t) {
                float hn = (accs[t][r] - mu) * rs * gt[t] + bt[t];
                Hb[row * HSTR + t * 16 + m16] = hn;   // overwrites A2 (consumed)
            }
        }
        // residual back in lane=channel layout
#pragma unroll
        for (int m = 0; m < 16; ++m) bev[m] = b2[m] + Hb[m * HSTR + lane];
    }

    // z-mean, write two tmp rows (coalesced; transpose kernel finishes layout)
#pragma unroll
    for (int p = 0; p < 2; ++p) {
        float s = 0.0f;
#pragma unroll
        for (int z = 0; z < ZD; ++z) s += bev[p * 8 + z];
        tmp[(2 * wid2 + p) * ED + lane] = s * 0.125f;
    }
}

// tmp (Y*X, E) -> out (E, Y*X) via LDS tile transpose (fully coalesced both ways)
__global__ __launch_bounds__(256) void k_transpose(const float* __restrict__ tmp,
                                                   float* __restrict__ out) {
    __shared__ float tile[64][65];
    const int p0 = blockIdx.x * 64;
    const int lane = threadIdx.x & 63;
    const int r = threadIdx.x >> 6;
#pragma unroll
    for (int i = 0; i < 16; ++i) {
        int row = r + 4 * i;
        tile[row][lane] = tmp[(p0 + row) * ED + lane];
    }
    __syncthreads();
#pragma unroll
    for (int i = 0; i < 16; ++i) {
        int erow = r + 4 * i;
        out[erow * (YD * XD) + p0 + lane] = tile[lane][erow];
    }
}

extern "C" void kernel_launch(void* const* d_in, const int* in_sizes, int n_in,
                              void* d_out, int out_size, void* d_ws, size_t ws_size,
                              hipStream_t stream) {
    const float* Tv      = (const float*)d_in[0];
    const float* intr    = (const float*)d_in[1];
    const float* img     = (const float*)d_in[2];
    const float* bev_in  = (const float*)d_in[3];
    const float* W_off   = (const float*)d_in[4];
    const float* b_off   = (const float*)d_in[5];
    const float* s_off   = (const float*)d_in[6];
    const float* W_w     = (const float*)d_in[7];
    const float* b_w     = (const float*)d_in[8];
    const float* W_l     = (const float*)d_in[9];
    const float* b_l     = (const float*)d_in[10];
    const float* ln_g    = (const float*)d_in[11];
    const float* ln_b    = (const float*)d_in[12];
    float* out = (float*)d_out;

    char* ws = (char*)d_ws;
    unsigned short* imgHWC = (unsigned short*)ws;              // 3,932,160 B + 128 B guard
    float* tmp = (float*)(ws + 3932288);                       // 4,194,304 B
    unsigned short* W9f = (unsigned short*)(ws + 3932288 + 4194304);        // 6,144 B
    unsigned short* Wlf = (unsigned short*)(ws + 3932288 + 4194304 + 6144); // 24,576 B

    // prep: img transpose->bf16 (480 blocks) + weight frags + guard zero (8 blocks)
    k_prep<<<(FHD * FWD) / 64 + 8, 256, 0, stream>>>(img, imgHWC, W_off, W_w, W_l,
                                                     W9f, Wlf);
    // main fused loop: 8192 waves, 2 points each; coalesced tmp writes
    k_main<<<(XD * YD / 2) / 4, 256, 0, stream>>>(Tv, intr, imgHWC, bev_in,
                                                  W9f, Wlf, b_off, s_off, b_w,
                                                  b_l, ln_g, ln_b, tmp);
    // transpose (Y*X,E) -> (E,Y*X)
    k_transpose<<<(YD * XD) / 64, 256, 0, stream>>>(tmp, out);
}

// Round 10
// 161.612 us; speedup vs baseline: 1.0819x; 1.0819x over previous
//
#include <hip/hip_runtime.h>
#include <math.h>

// Problem constants
#define XD 128
#define YD 128
#define ZD 8
#define ED 64
#define KD 3
#define NITER 3
#define FHD 96
#define FWD 320
#define HALF_W 640.0f
#define HALF_H 192.0f

#define ASTRIDE 80   // shorts per A-tile row (160 B: 16B-aligned; ~zero conflicts R3/R4/R7)
#define DSTR 28      // floats per logit-tile row
#define HSTR 68      // floats per H-tile row

// Single per-wave LDS UNION region (serial wave-private lifetimes, in-order DS):
//   Ab bf16 A-tile (16*80*2 = 2560 B)  ->  Db logits (16*28*4 = 1792 B)
//   -> Ab (stage 2) -> Hb (16*68*4 = 4352 B)
#define WAVE_LDS 4352

typedef __attribute__((ext_vector_type(8))) short short8;
typedef __attribute__((ext_vector_type(4))) float f32x4;
typedef float          __attribute__((may_alias)) fal;
typedef unsigned       __attribute__((may_alias)) ual;
typedef unsigned short __attribute__((may_alias)) usal;

__device__ __forceinline__ unsigned short f2bf(float f) {
    unsigned u = __float_as_uint(f);
    u += 0x7fff + ((u >> 16) & 1);
    return (unsigned short)(u >> 16);
}

__device__ __forceinline__ float rdlane_f(float v, int s) {
    return __int_as_float(__builtin_amdgcn_readlane(__float_as_int(v), s));
}

// sum over each 16-lane DPP row via row_ror 1,2,4,8 (pure VALU, no DS pipe)
__device__ __forceinline__ float rowsum16(float v) {
    v += __int_as_float(__builtin_amdgcn_update_dpp(0, __float_as_int(v), 0x121, 0xf, 0xf, true));
    v += __int_as_float(__builtin_amdgcn_update_dpp(0, __float_as_int(v), 0x122, 0xf, 0xf, true));
    v += __int_as_float(__builtin_amdgcn_update_dpp(0, __float_as_int(v), 0x124, 0xf, 0xf, true));
    v += __int_as_float(__builtin_amdgcn_update_dpp(0, __float_as_int(v), 0x128, 0xf, 0xf, true));
    return v;
}

// ---- prep: img CHW -> paired-column bf16 HWC (blocks 0..479) + weight frags ----
// imgP[hw][e] = u32{ bf16 img[e][hw] | bf16 img[e][hw+1] << 16 }, second slot = 0
// at x = FW-1. Since 320 = 5*64, the x-edge (x=319) falls exactly at row 63 of
// blocks with hw0 % 320 == 256 — so only the row==63 path needs the edge check.
__global__ __launch_bounds__(256) void k_prep(const float* __restrict__ img,
                                              unsigned* __restrict__ imgP,
                                              const float* __restrict__ W_off,
                                              const float* __restrict__ W_w,
                                              const float* __restrict__ W_l,
                                              unsigned short* __restrict__ W9f,
                                              unsigned short* __restrict__ Wlf) {
    if (blockIdx.x < (FHD * FWD) / 64) {
        __shared__ float tile[64][65];
        const int hw0 = blockIdx.x * 64;
        const int lane = threadIdx.x & 63;
        const int r = threadIdx.x >> 6;
#pragma unroll
        for (int i = 0; i < 16; ++i) {
            int e = r + 4 * i;
            tile[e][lane] = img[e * (FHD * FWD) + hw0 + lane];
        }
        __syncthreads();
        const bool edge_block = ((hw0 % FWD) == FWD - 64);  // row63 is x=319
#pragma unroll
        for (int i = 0; i < 16; ++i) {
            int row = r + 4 * i;
            float v1 = tile[lane][row];
            float v2;
            if (row < 63) {
                v2 = tile[lane][row + 1];
            } else {
                v2 = edge_block ? 0.0f : img[lane * (FHD * FWD) + hw0 + 64];
            }
            imgP[(hw0 + row) * 64 + lane] =
                (unsigned)f2bf(v1) | ((unsigned)f2bf(v2) << 16);
        }
    } else {
        int idx = (blockIdx.x - (FHD * FWD) / 64) * 256 + threadIdx.x;
        if (idx < 3 * 4 * 2 * 64) {
            int lane = idx & 63, s = (idx >> 6) & 1, t = (idx >> 7) & 3, i = idx >> 9;
            int n = t * 16 + (lane & 15), quad = lane >> 4;
#pragma unroll
            for (int jj = 0; jj < 8; ++jj) {
                int ep = s * 32 + quad * 8 + jj;
                Wlf[idx * 8 + jj] = f2bf(W_l[(i * ED + ep) * ED + n]);
            }
        } else if (idx < 3 * 4 * 2 * 64 + 3 * 2 * 64) {
            int k = idx - 3 * 4 * 2 * 64;
            int lane = k & 63, s = (k >> 6) & 1, i = k >> 7;
            int n = lane & 15, quad = lane >> 4;
#pragma unroll
            for (int jj = 0; jj < 8; ++jj) {
                int ep = s * 32 + quad * 8 + jj;
                float v = 0.0f;
                if (n < 6) v = W_off[(i * ED + ep) * 6 + n];
                else if (n < 9) v = W_w[(i * ED + ep) * 3 + (n - 6)];
                W9f[k * 8 + jj] = f2bf(v);
            }
        }
    }
}

// -------- main fused kernel: one wave per TWO (x,y) points, 16 MFMA rows --------
__global__ __launch_bounds__(256, 4) void k_main(
    const float* __restrict__ Tv,     // (3,4)
    const float* __restrict__ intr,   // (3,3)
    const unsigned* __restrict__ imgP,// (FH*FW, E) paired-column bf16
    const float* __restrict__ bev_in, // (X,Y,Z,E)
    const unsigned short* __restrict__ W9f,
    const unsigned short* __restrict__ Wlf,
    const float* __restrict__ b_off,  // (I,6)
    const float* __restrict__ s_off,  // (I,)
    const float* __restrict__ b_w,    // (I,3)
    const float* __restrict__ b_l,    // (I,E)
    const float* __restrict__ ln_g,   // (I,E)
    const float* __restrict__ ln_b,   // (I,E)
    float* __restrict__ tmp)          // (Y*X, E)
{
    __shared__ __align__(16) char smem[4 * WAVE_LDS];

    const int lane = threadIdx.x & 63;
    const int wv = threadIdx.x >> 6;
    const int wid2 = __builtin_amdgcn_readfirstlane(blockIdx.x * 4 + wv);
    const int m16 = lane & 15;
    const int quad = lane >> 4;

    char* base = smem + wv * WAVE_LDS;
    usal* Ab = (usal*)base;
    fal*  Db = (fal*)base;
    fal*  Hb = (fal*)base;

    const char* imgB = (const char*)imgP;

    // T = intr @ Tv (3x4), uniform
    float T[12];
#pragma unroll
    for (int r = 0; r < 3; ++r)
#pragma unroll
        for (int c = 0; c < 4; ++c)
            T[r * 4 + c] = intr[r * 3 + 0] * Tv[0 * 4 + c] +
                           intr[r * 3 + 1] * Tv[1 * 4 + c] +
                           intr[r * 3 + 2] * Tv[2 * 4 + c];

    // per-lane descriptor identity: lane s handles sample (m = s/3, k = s%3), s<48
    const int sm = min(lane / 3, 15);
    const int sk = lane - (lane / 3) * 3;

    // per-lane projected base coords for row sm
    float cxd, cyd;
    {
        int p = sm >> 3, z = sm & 7;
        int q = 2 * wid2 + p;
        int x = q & (XD - 1);
        int y = q >> 7;
        float gx = x * 0.8f;
        float gy = 51.2f - y * 0.8f;
        float gz = z * 0.5f - 2.5f;
        float p0 = T[0] * gx + T[1] * gy + T[2] * gz + T[3];
        float p1 = T[4] * gx + T[5] * gy + T[6] * gz + T[7];
        float p2 = T[8] * gx + T[9] * gy + T[10] * gz + T[11];
        cxd = (p0 / p2) / HALF_W - 1.0f;
        cyd = (p1 / p2) / HALF_H - 1.0f;
    }

    // two points per wave; rows m = p*8 + z
    float bev[16];
#pragma unroll
    for (int p = 0; p < 2; ++p) {
        int q = 2 * wid2 + p;
        int x = q & (XD - 1);
        int y = q >> 7;
        int pbase = (((x << 7) | y) << 9);
#pragma unroll
        for (int z = 0; z < ZD; ++z)
            bev[p * 8 + z] = bev_in[pbase + z * ED + lane];
    }

    for (int i = 0; i < NITER; ++i) {
        // ---- stage 1: logits = bev(16x64) @ W9(64x9) via 2 MFMAs ----
#pragma unroll
        for (int m = 0; m < 16; ++m) Ab[m * ASTRIDE + lane] = f2bf(bev[m]);

        short8 wb0 = *(const short8*)(W9f + ((i * 2 + 0) * 64 + lane) * 8);
        short8 wb1 = *(const short8*)(W9f + ((i * 2 + 1) * 64 + lane) * 8);
        short8 a0 = *(const short8*)(Ab + m16 * ASTRIDE + quad * 8);
        short8 a1 = *(const short8*)(Ab + m16 * ASTRIDE + 32 + quad * 8);
        f32x4 dlog = {0.0f, 0.0f, 0.0f, 0.0f};
        dlog = __builtin_amdgcn_mfma_f32_16x16x32_bf16(a0, wb0, dlog, 0, 0, 0);
        dlog = __builtin_amdgcn_mfma_f32_16x16x32_bf16(a1, wb1, dlog, 0, 0, 0);
        // D-layout -> Db (overwrites A-tile region; A already consumed)
#pragma unroll
        for (int r = 0; r < 4; ++r) Db[(quad * 4 + r) * DSTR + m16] = dlog[r];

        const float so = s_off[i];
        const float bo0 = b_off[i * 6 + 0], bo1 = b_off[i * 6 + 1], bo2 = b_off[i * 6 + 2];
        const float bo3 = b_off[i * 6 + 3], bo4 = b_off[i * 6 + 4], bo5 = b_off[i * 6 + 5];
        const float bw0 = b_w[i * 3 + 0], bw1 = b_w[i * 3 + 1], bw2 = b_w[i * 3 + 2];

        // ---- lane-parallel sample descriptors, kept in REGISTERS ----
        int rowA, rowB;
        float dw0, dw1, dw2, dw3;
        {
            const fal* Dm = Db + sm * DSTR;
            f32x4 qa = *(const f32x4*)(Dm);       // logits 0..3
            f32x4 qb = *(const f32x4*)(Dm + 4);   // logits 4..7
            float l8 = Dm[8];

            float ox0 = (qa[0] + bo0) * so, oy0 = (qa[1] + bo1) * so;
            float ox1 = (qa[2] + bo2) * so, oy1 = (qa[3] + bo3) * so;
            float ox2 = (qb[0] + bo4) * so, oy2 = (qb[1] + bo5) * so;
            float l0 = qb[2] + bw0, l1 = qb[3] + bw1, l2 = l8 + bw2;
            float mx = fmaxf(fmaxf(l0, l1), l2);
            float e0 = __expf(l0 - mx), e1 = __expf(l1 - mx), e2 = __expf(l2 - mx);
            float inv = 1.0f / (e0 + e1 + e2);
            float wk0 = e0 * inv, wk1 = e1 * inv, wk2 = e2 * inv;

            float wkk = (sk == 0) ? wk0 : ((sk == 1) ? wk1 : wk2);
            float ox  = (sk == 0) ? ox0 : ((sk == 1) ? ox1 : ox2);
            float oy  = (sk == 0) ? oy0 : ((sk == 1) ? oy1 : oy2);

            float gxx = cxd + ox, gyy = cyd + oy;
            float px = ((gxx + 1.0f) * (float)FWD - 1.0f) * 0.5f;
            float py = ((gyy + 1.0f) * (float)FHD - 1.0f) * 0.5f;
            float x0f = floorf(px), y0f = floorf(py);
            float fx = px - x0f, fy = py - y0f;
            int ix0 = (int)x0f, iy0 = (int)y0f;
            int iy1 = iy0 + 1;

            int cb = min(max(ix0, 0), FWD - 1);
            float wA = (ix0 >= 0 && ix0 < FWD) ? (1.0f - fx)
                                               : ((ix0 == -1) ? fx : 0.0f);
            float wB = (ix0 >= 0 && ix0 + 1 < FWD) ? fx : 0.0f;

            int rb0 = min(max(iy0, 0), FHD - 1);
            int rb1 = min(max(iy1, 0), FHD - 1);
            float wy0v = (iy0 >= 0 && iy0 < FHD) ? (1.0f - fy) : 0.0f;
            float wy1v = (iy1 >= 0 && iy1 < FHD) ? fy : 0.0f;

            rowA = rb0 * FWD + cb;          // paired entry covers cols cb, cb+1
            rowB = rb1 * FWD + cb;
            dw0 = wkk * wA * wy0v;          // (rowA, col cb)
            dw1 = wkk * wB * wy0v;          // (rowA, col cb+1)
            dw2 = wkk * wA * wy1v;          // (rowB, col cb)
            dw3 = wkk * wB * wy1v;          // (rowB, col cb+1)
        }

        // ---- sampling: readlane -> SGPR bases/weights; ONE dword load per corner
        //      pair (both x-columns), unpack via shift/and — 2 loads per sample ----
        float b2[16];
#pragma unroll
        for (int m = 0; m < 16; ++m) {
            float fA0 = 0.0f, fA1 = 0.0f, fB0 = 0.0f, fB1 = 0.0f;
#pragma unroll
            for (int k = 0; k < KD; ++k) {
                const int s = m * 3 + k;
                int offA = __builtin_amdgcn_readlane(rowA, s);
                int offB = __builtin_amdgcn_readlane(rowB, s);
                float w0 = rdlane_f(dw0, s);
                float w1 = rdlane_f(dw1, s);
                float w2 = rdlane_f(dw2, s);
                float w3 = rdlane_f(dw3, s);
                const ual* pA = (const ual*)(imgB + ((size_t)(unsigned)offA << 8)) + lane;
                const ual* pB = (const ual*)(imgB + ((size_t)(unsigned)offB << 8)) + lane;
                unsigned uA = *pA, uB = *pB;
                float vA0 = __int_as_float((int)(uA << 16));
                float vA1 = __int_as_float((int)(uA & 0xffff0000u));
                float vB0 = __int_as_float((int)(uB << 16));
                float vB1 = __int_as_float((int)(uB & 0xffff0000u));
                fA0 = fmaf(w0, vA0, fA0);
                fA1 = fmaf(w1, vA1, fA1);
                fB0 = fmaf(w2, vB0, fB0);
                fB1 = fmaf(w3, vB1, fB1);
            }
            b2[m] = bev[m] + ((fA0 + fA1) + (fB0 + fB1));  // bev_mid
        }

        // ---- stage 2: h = bev_mid(16x64) @ W_l + b_l via 8 MFMAs ----
#pragma unroll
        for (int m = 0; m < 16; ++m) Ab[m * ASTRIDE + lane] = f2bf(b2[m]);
        short8 a0b = *(const short8*)(Ab + m16 * ASTRIDE + quad * 8);
        short8 a1b = *(const short8*)(Ab + m16 * ASTRIDE + 32 + quad * 8);
        f32x4 accs[4];
#pragma unroll
        for (int t = 0; t < 4; ++t) {
            float bb = b_l[i * ED + t * 16 + m16];
            f32x4 acc = {bb, bb, bb, bb};
            short8 w0 = *(const short8*)(Wlf + (((i * 4 + t) * 2 + 0) * 64 + lane) * 8);
            short8 w1 = *(const short8*)(Wlf + (((i * 4 + t) * 2 + 1) * 64 + lane) * 8);
            acc = __builtin_amdgcn_mfma_f32_16x16x32_bf16(a0b, w0, acc, 0, 0, 0);
            acc = __builtin_amdgcn_mfma_f32_16x16x32_bf16(a1b, w1, acc, 0, 0, 0);
            accs[t] = acc;
        }

        // ---- LayerNorm in D-layout: rows quad*4+r, cols t*16+m16 (DPP row-sums) ----
        float s1[4], s2[4];
#pragma unroll
        for (int r = 0; r < 4; ++r) {
            s1[r] = accs[0][r] + accs[1][r] + accs[2][r] + accs[3][r];
            s2[r] = accs[0][r] * accs[0][r];
            s2[r] = fmaf(accs[1][r], accs[1][r], s2[r]);
            s2[r] = fmaf(accs[2][r], accs[2][r], s2[r]);
            s2[r] = fmaf(accs[3][r], accs[3][r], s2[r]);
            s1[r] = rowsum16(s1[r]);
            s2[r] = rowsum16(s2[r]);
        }
        float gt[4], bt[4];
#pragma unroll
        for (int t = 0; t < 4; ++t) {
            gt[t] = ln_g[i * ED + t * 16 + m16];
            bt[t] = ln_b[i * ED + t * 16 + m16];
        }
#pragma unroll
        for (int r = 0; r < 4; ++r) {
            float mu = s1[r] * (1.0f / 64.0f);
            float var = fmaxf(s2[r] * (1.0f / 64.0f) - mu * mu, 0.0f);
            float rs = rsqrtf(var + 1e-5f);
            int row = quad * 4 + r;
#pragma unroll
            for (int t = 0; t < 4; ++t) {
                float hn = (accs[t][r] - mu) * rs * gt[t] + bt[t];
                Hb[row * HSTR + t * 16 + m16] = hn;   // overwrites A2 (consumed)
            }
        }
        // residual back in lane=channel layout
#pragma unroll
        for (int m = 0; m < 16; ++m) bev[m] = b2[m] + Hb[m * HSTR + lane];
    }

    // z-mean, write two tmp rows (coalesced; transpose kernel finishes layout)
#pragma unroll
    for (int p = 0; p < 2; ++p) {
        float s = 0.0f;
#pragma unroll
        for (int z = 0; z < ZD; ++z) s += bev[p * 8 + z];
        tmp[(2 * wid2 + p) * ED + lane] = s * 0.125f;
    }
}

// tmp (Y*X, E) -> out (E, Y*X) via LDS tile transpose (fully coalesced both ways)
__global__ __launch_bounds__(256) void k_transpose(const float* __restrict__ tmp,
                                                   float* __restrict__ out) {
    __shared__ float tile[64][65];
    const int p0 = blockIdx.x * 64;
    const int lane = threadIdx.x & 63;
    const int r = threadIdx.x >> 6;
#pragma unroll
    for (int i = 0; i < 16; ++i) {
        int row = r + 4 * i;
        tile[row][lane] = tmp[(p0 + row) * ED + lane];
    }
    __syncthreads();
#pragma unroll
    for (int i = 0; i < 16; ++i) {
        int erow = r + 4 * i;
        out[erow * (YD * XD) + p0 + lane] = tile[lane][erow];
    }
}

extern "C" void kernel_launch(void* const* d_in, const int* in_sizes, int n_in,
                              void* d_out, int out_size, void* d_ws, size_t ws_size,
                              hipStream_t stream) {
    const float* Tv      = (const float*)d_in[0];
    const float* intr    = (const float*)d_in[1];
    const float* img     = (const float*)d_in[2];
    const float* bev_in  = (const float*)d_in[3];
    const float* W_off   = (const float*)d_in[4];
    const float* b_off   = (const float*)d_in[5];
    const float* s_off   = (const float*)d_in[6];
    const float* W_w     = (const float*)d_in[7];
    const float* b_w     = (const float*)d_in[8];
    const float* W_l     = (const float*)d_in[9];
    const float* b_l     = (const float*)d_in[10];
    const float* ln_g    = (const float*)d_in[11];
    const float* ln_b    = (const float*)d_in[12];
    float* out = (float*)d_out;

    char* ws = (char*)d_ws;
    unsigned* imgP = (unsigned*)ws;                            // 7,864,320 B
    float* tmp = (float*)(ws + 7864320);                       // 4,194,304 B
    unsigned short* W9f = (unsigned short*)(ws + 7864320 + 4194304);        // 6,144 B
    unsigned short* Wlf = (unsigned short*)(ws + 7864320 + 4194304 + 6144); // 24,576 B

    // prep: paired-column bf16 image (480 blocks) + weight frags (8 blocks)
    k_prep<<<(FHD * FWD) / 64 + 8, 256, 0, stream>>>(img, imgP, W_off, W_w, W_l,
                                                     W9f, Wlf);
    // main fused loop: 8192 waves, 2 points each; coalesced tmp writes
    k_main<<<(XD * YD / 2) / 4, 256, 0, stream>>>(Tv, intr, imgP, bev_in,
                                                  W9f, Wlf, b_off, s_off, b_w,
                                                  b_l, ln_g, ln_b, tmp);
    // transpose (Y*X,E) -> (E,Y*X)
    k_transpose<<<(YD * XD) / 64, 256, 0, stream>>>(tmp, out);
}

// Round 11
// 147.641 us; speedup vs baseline: 1.1843x; 1.0946x over previous
//
#include <hip/hip_runtime.h>
#include <math.h>

// Problem constants
#define XD 128
#define YD 128
#define ZD 8
#define ED 64
#define KD 3
#define NITER 3
#define FHD 96
#define FWD 320
#define HALF_W 640.0f
#define HALF_H 192.0f

#define ASTRIDE 80   // shorts per A-tile row (160 B: 16B-aligned; ~zero conflicts R3/R4/R7)
#define DSTR 28      // floats per logit-tile row
#define HSTR 68      // floats per H-tile row

// Single per-wave LDS UNION region (serial wave-private lifetimes, in-order DS):
//   Ab bf16 A-tile (16*80*2 = 2560 B)  ->  Db logits (16*28*4 = 1792 B)
//   -> Ab (stage 2) -> Hb (16*68*4 = 4352 B)
#define WAVE_LDS 4352

typedef __attribute__((ext_vector_type(8))) short short8;
typedef __attribute__((ext_vector_type(4))) float f32x4;
typedef float          __attribute__((may_alias)) fal;
typedef unsigned       __attribute__((may_alias)) ual;
typedef unsigned short __attribute__((may_alias)) usal;

__device__ __forceinline__ unsigned short f2bf(float f) {
    unsigned u = __float_as_uint(f);
    u += 0x7fff + ((u >> 16) & 1);
    return (unsigned short)(u >> 16);
}

// pack two fp32 into a bf16-pair u32 (lo = a, hi = b), RNE
__device__ __forceinline__ int pk2bf(float a, float b) {
    return (int)((unsigned)f2bf(a) | ((unsigned)f2bf(b) << 16));
}

// acc += a.lo*b.lo + a.hi*b.hi  (bf16 pairs, f32 accumulate)
__device__ __forceinline__ float dot2bf(float acc, unsigned a, int b) {
#if defined(__has_builtin) && __has_builtin(__builtin_amdgcn_fdot2_f32_bf16)
    typedef __bf16 bf16x2 __attribute__((ext_vector_type(2)));
    union U { unsigned u; bf16x2 v; };
    U ua, ub;
    ua.u = a;
    ub.u = (unsigned)b;
    return __builtin_amdgcn_fdot2_f32_bf16(ua.v, ub.v, acc, false);
#else
    asm("v_dot2_f32_bf16 %0, %1, %2, %0" : "+v"(acc) : "v"(a), "s"(b));
    return acc;
#endif
}

// sum over each 16-lane DPP row via row_ror 1,2,4,8 (pure VALU, no DS pipe)
__device__ __forceinline__ float rowsum16(float v) {
    v += __int_as_float(__builtin_amdgcn_update_dpp(0, __float_as_int(v), 0x121, 0xf, 0xf, true));
    v += __int_as_float(__builtin_amdgcn_update_dpp(0, __float_as_int(v), 0x122, 0xf, 0xf, true));
    v += __int_as_float(__builtin_amdgcn_update_dpp(0, __float_as_int(v), 0x124, 0xf, 0xf, true));
    v += __int_as_float(__builtin_amdgcn_update_dpp(0, __float_as_int(v), 0x128, 0xf, 0xf, true));
    return v;
}

// ---- prep: img CHW -> paired-column bf16 HWC (blocks 0..479) + weight frags ----
// imgP[hw][e] = u32{ bf16 img[e][hw] | bf16 img[e][hw+1] << 16 }, second slot = 0
// at x = FW-1 (320 = 5*64: the x-edge falls at row 63 of blocks hw0%320==256).
__global__ __launch_bounds__(256) void k_prep(const float* __restrict__ img,
                                              unsigned* __restrict__ imgP,
                                              const float* __restrict__ W_off,
                                              const float* __restrict__ W_w,
                                              const float* __restrict__ W_l,
                                              unsigned short* __restrict__ W9f,
                                              unsigned short* __restrict__ Wlf) {
    if (blockIdx.x < (FHD * FWD) / 64) {
        __shared__ float tile[64][65];
        const int hw0 = blockIdx.x * 64;
        const int lane = threadIdx.x & 63;
        const int r = threadIdx.x >> 6;
#pragma unroll
        for (int i = 0; i < 16; ++i) {
            int e = r + 4 * i;
            tile[e][lane] = img[e * (FHD * FWD) + hw0 + lane];
        }
        __syncthreads();
        const bool edge_block = ((hw0 % FWD) == FWD - 64);  // row63 is x=319
#pragma unroll
        for (int i = 0; i < 16; ++i) {
            int row = r + 4 * i;
            float v1 = tile[lane][row];
            float v2;
            if (row < 63) {
                v2 = tile[lane][row + 1];
            } else {
                v2 = edge_block ? 0.0f : img[lane * (FHD * FWD) + hw0 + 64];
            }
            imgP[(hw0 + row) * 64 + lane] =
                (unsigned)f2bf(v1) | ((unsigned)f2bf(v2) << 16);
        }
    } else {
        int idx = (blockIdx.x - (FHD * FWD) / 64) * 256 + threadIdx.x;
        if (idx < 3 * 4 * 2 * 64) {
            int lane = idx & 63, s = (idx >> 6) & 1, t = (idx >> 7) & 3, i = idx >> 9;
            int n = t * 16 + (lane & 15), quad = lane >> 4;
#pragma unroll
            for (int jj = 0; jj < 8; ++jj) {
                int ep = s * 32 + quad * 8 + jj;
                Wlf[idx * 8 + jj] = f2bf(W_l[(i * ED + ep) * ED + n]);
            }
        } else if (idx < 3 * 4 * 2 * 64 + 3 * 2 * 64) {
            int k = idx - 3 * 4 * 2 * 64;
            int lane = k & 63, s = (k >> 6) & 1, i = k >> 7;
            int n = lane & 15, quad = lane >> 4;
#pragma unroll
            for (int jj = 0; jj < 8; ++jj) {
                int ep = s * 32 + quad * 8 + jj;
                float v = 0.0f;
                if (n < 6) v = W_off[(i * ED + ep) * 6 + n];
                else if (n < 9) v = W_w[(i * ED + ep) * 3 + (n - 6)];
                W9f[k * 8 + jj] = f2bf(v);
            }
        }
    }
}

// -------- main fused kernel: one wave per TWO (x,y) points, 16 MFMA rows --------
__global__ __launch_bounds__(256, 4) void k_main(
    const float* __restrict__ Tv,     // (3,4)
    const float* __restrict__ intr,   // (3,3)
    const unsigned* __restrict__ imgP,// (FH*FW, E) paired-column bf16
    const float* __restrict__ bev_in, // (X,Y,Z,E)
    const unsigned short* __restrict__ W9f,
    const unsigned short* __restrict__ Wlf,
    const float* __restrict__ b_off,  // (I,6)
    const float* __restrict__ s_off,  // (I,)
    const float* __restrict__ b_w,    // (I,3)
    const float* __restrict__ b_l,    // (I,E)
    const float* __restrict__ ln_g,   // (I,E)
    const float* __restrict__ ln_b,   // (I,E)
    float* __restrict__ tmp)          // (Y*X, E)
{
    __shared__ __align__(16) char smem[4 * WAVE_LDS];

    const int lane = threadIdx.x & 63;
    const int wv = threadIdx.x >> 6;
    const int wid2 = __builtin_amdgcn_readfirstlane(blockIdx.x * 4 + wv);
    const int m16 = lane & 15;
    const int quad = lane >> 4;

    char* base = smem + wv * WAVE_LDS;
    usal* Ab = (usal*)base;
    fal*  Db = (fal*)base;
    fal*  Hb = (fal*)base;

    const char* imgB = (const char*)imgP;

    // T = intr @ Tv (3x4), uniform
    float T[12];
#pragma unroll
    for (int r = 0; r < 3; ++r)
#pragma unroll
        for (int c = 0; c < 4; ++c)
            T[r * 4 + c] = intr[r * 3 + 0] * Tv[0 * 4 + c] +
                           intr[r * 3 + 1] * Tv[1 * 4 + c] +
                           intr[r * 3 + 2] * Tv[2 * 4 + c];

    // per-lane descriptor identity: lane s handles sample (m = s/3, k = s%3), s<48
    const int sm = min(lane / 3, 15);
    const int sk = lane - (lane / 3) * 3;

    // per-lane projected base coords for row sm
    float cxd, cyd;
    {
        int p = sm >> 3, z = sm & 7;
        int q = 2 * wid2 + p;
        int x = q & (XD - 1);
        int y = q >> 7;
        float gx = x * 0.8f;
        float gy = 51.2f - y * 0.8f;
        float gz = z * 0.5f - 2.5f;
        float p0 = T[0] * gx + T[1] * gy + T[2] * gz + T[3];
        float p1 = T[4] * gx + T[5] * gy + T[6] * gz + T[7];
        float p2 = T[8] * gx + T[9] * gy + T[10] * gz + T[11];
        cxd = (p0 / p2) / HALF_W - 1.0f;
        cyd = (p1 / p2) / HALF_H - 1.0f;
    }

    // two points per wave; rows m = p*8 + z
    float bev[16];
#pragma unroll
    for (int p = 0; p < 2; ++p) {
        int q = 2 * wid2 + p;
        int x = q & (XD - 1);
        int y = q >> 7;
        int pbase = (((x << 7) | y) << 9);
#pragma unroll
        for (int z = 0; z < ZD; ++z)
            bev[p * 8 + z] = bev_in[pbase + z * ED + lane];
    }

    for (int i = 0; i < NITER; ++i) {
        // ---- stage 1: logits = bev(16x64) @ W9(64x9) via 2 MFMAs ----
#pragma unroll
        for (int m = 0; m < 16; ++m) Ab[m * ASTRIDE + lane] = f2bf(bev[m]);

        short8 wb0 = *(const short8*)(W9f + ((i * 2 + 0) * 64 + lane) * 8);
        short8 wb1 = *(const short8*)(W9f + ((i * 2 + 1) * 64 + lane) * 8);
        short8 a0 = *(const short8*)(Ab + m16 * ASTRIDE + quad * 8);
        short8 a1 = *(const short8*)(Ab + m16 * ASTRIDE + 32 + quad * 8);
        f32x4 dlog = {0.0f, 0.0f, 0.0f, 0.0f};
        dlog = __builtin_amdgcn_mfma_f32_16x16x32_bf16(a0, wb0, dlog, 0, 0, 0);
        dlog = __builtin_amdgcn_mfma_f32_16x16x32_bf16(a1, wb1, dlog, 0, 0, 0);
        // D-layout -> Db (overwrites A-tile region; A already consumed)
#pragma unroll
        for (int r = 0; r < 4; ++r) Db[(quad * 4 + r) * DSTR + m16] = dlog[r];

        const float so = s_off[i];
        const float bo0 = b_off[i * 6 + 0], bo1 = b_off[i * 6 + 1], bo2 = b_off[i * 6 + 2];
        const float bo3 = b_off[i * 6 + 3], bo4 = b_off[i * 6 + 4], bo5 = b_off[i * 6 + 5];
        const float bw0 = b_w[i * 3 + 0], bw1 = b_w[i * 3 + 1], bw2 = b_w[i * 3 + 2];

        // ---- lane-parallel sample descriptors, packed, kept in REGISTERS ----
        int rowAB;        // u16 pair: rowA | rowB<<16
        int w01, w23;     // bf16 pairs: (col cb, col cb+1) weights for rows A,B
        {
            const fal* Dm = Db + sm * DSTR;
            f32x4 qa = *(const f32x4*)(Dm);       // logits 0..3
            f32x4 qb = *(const f32x4*)(Dm + 4);   // logits 4..7
            float l8 = Dm[8];

            float ox0 = (qa[0] + bo0) * so, oy0 = (qa[1] + bo1) * so;
            float ox1 = (qa[2] + bo2) * so, oy1 = (qa[3] + bo3) * so;
            float ox2 = (qb[0] + bo4) * so, oy2 = (qb[1] + bo5) * so;
            float l0 = qb[2] + bw0, l1 = qb[3] + bw1, l2 = l8 + bw2;
            float mx = fmaxf(fmaxf(l0, l1), l2);
            float e0 = __expf(l0 - mx), e1 = __expf(l1 - mx), e2 = __expf(l2 - mx);
            float inv = 1.0f / (e0 + e1 + e2);
            float wk0 = e0 * inv, wk1 = e1 * inv, wk2 = e2 * inv;

            float wkk = (sk == 0) ? wk0 : ((sk == 1) ? wk1 : wk2);
            float ox  = (sk == 0) ? ox0 : ((sk == 1) ? ox1 : ox2);
            float oy  = (sk == 0) ? oy0 : ((sk == 1) ? oy1 : oy2);

            float gxx = cxd + ox, gyy = cyd + oy;
            float px = ((gxx + 1.0f) * (float)FWD - 1.0f) * 0.5f;
            float py = ((gyy + 1.0f) * (float)FHD - 1.0f) * 0.5f;
            float x0f = floorf(px), y0f = floorf(py);
            float fx = px - x0f, fy = py - y0f;
            int ix0 = (int)x0f, iy0 = (int)y0f;
            int iy1 = iy0 + 1;

            int cb = min(max(ix0, 0), FWD - 1);
            float wA = (ix0 >= 0 && ix0 < FWD) ? (1.0f - fx)
                                               : ((ix0 == -1) ? fx : 0.0f);
            float wB = (ix0 >= 0 && ix0 + 1 < FWD) ? fx : 0.0f;

            int rb0 = min(max(iy0, 0), FHD - 1);
            int rb1 = min(max(iy1, 0), FHD - 1);
            float wy0v = (iy0 >= 0 && iy0 < FHD) ? (1.0f - fy) : 0.0f;
            float wy1v = (iy1 >= 0 && iy1 < FHD) ? fy : 0.0f;

            rowAB = (rb0 * FWD + cb) | ((rb1 * FWD + cb) << 16);
            w01 = pk2bf(wkk * wA * wy0v, wkk * wB * wy0v);
            w23 = pk2bf(wkk * wA * wy1v, wkk * wB * wy1v);
        }

        // ---- sampling: 3 readlanes + 2 dword loads + 2 dot2 per sample ----
        float b2[16];
#pragma unroll
        for (int m = 0; m < 16; ++m) {
            float fA = 0.0f, fB = 0.0f;
#pragma unroll
            for (int k = 0; k < KD; ++k) {
                const int s = m * 3 + k;
                unsigned rAB = (unsigned)__builtin_amdgcn_readlane(rowAB, s);
                int wa = __builtin_amdgcn_readlane(w01, s);
                int wb = __builtin_amdgcn_readlane(w23, s);
                size_t offA = (size_t)(rAB & 0xffffu) << 8;   // SALU
                size_t offB = (size_t)(rAB >> 16) << 8;       // SALU
                const ual* pA = (const ual*)(imgB + offA) + lane;
                const ual* pB = (const ual*)(imgB + offB) + lane;
                unsigned uA = *pA, uB = *pB;
                fA = dot2bf(fA, uA, wa);
                fB = dot2bf(fB, uB, wb);
            }
            b2[m] = bev[m] + (fA + fB);  // bev_mid
        }

        // ---- stage 2: h = bev_mid(16x64) @ W_l + b_l via 8 MFMAs ----
#pragma unroll
        for (int m = 0; m < 16; ++m) Ab[m * ASTRIDE + lane] = f2bf(b2[m]);
        short8 a0b = *(const short8*)(Ab + m16 * ASTRIDE + quad * 8);
        short8 a1b = *(const short8*)(Ab + m16 * ASTRIDE + 32 + quad * 8);
        f32x4 accs[4];
#pragma unroll
        for (int t = 0; t < 4; ++t) {
            float bb = b_l[i * ED + t * 16 + m16];
            f32x4 acc = {bb, bb, bb, bb};
            short8 w0 = *(const short8*)(Wlf + (((i * 4 + t) * 2 + 0) * 64 + lane) * 8);
            short8 w1 = *(const short8*)(Wlf + (((i * 4 + t) * 2 + 1) * 64 + lane) * 8);
            acc = __builtin_amdgcn_mfma_f32_16x16x32_bf16(a0b, w0, acc, 0, 0, 0);
            acc = __builtin_amdgcn_mfma_f32_16x16x32_bf16(a1b, w1, acc, 0, 0, 0);
            accs[t] = acc;
        }

        // ---- LayerNorm in D-layout: rows quad*4+r, cols t*16+m16 (DPP row-sums) ----
        float s1[4], s2[4];
#pragma unroll
        for (int r = 0; r < 4; ++r) {
            s1[r] = accs[0][r] + accs[1][r] + accs[2][r] + accs[3][r];
            s2[r] = accs[0][r] * accs[0][r];
            s2[r] = fmaf(accs[1][r], accs[1][r], s2[r]);
            s2[r] = fmaf(accs[2][r], accs[2][r], s2[r]);
            s2[r] = fmaf(accs[3][r], accs[3][r], s2[r]);
            s1[r] = rowsum16(s1[r]);
            s2[r] = rowsum16(s2[r]);
        }
        float gt[4], bt[4];
#pragma unroll
        for (int t = 0; t < 4; ++t) {
            gt[t] = ln_g[i * ED + t * 16 + m16];
            bt[t] = ln_b[i * ED + t * 16 + m16];
        }
#pragma unroll
        for (int r = 0; r < 4; ++r) {
            float mu = s1[r] * (1.0f / 64.0f);
            float var = fmaxf(s2[r] * (1.0f / 64.0f) - mu * mu, 0.0f);
            float rs = rsqrtf(var + 1e-5f);
            int row = quad * 4 + r;
#pragma unroll
            for (int t = 0; t < 4; ++t) {
                float hn = (accs[t][r] - mu) * rs * gt[t] + bt[t];
                Hb[row * HSTR + t * 16 + m16] = hn;   // overwrites A2 (consumed)
            }
        }
        // residual back in lane=channel layout
#pragma unroll
        for (int m = 0; m < 16; ++m) bev[m] = b2[m] + Hb[m * HSTR + lane];
    }

    // z-mean, write two tmp rows (coalesced; transpose kernel finishes layout)
#pragma unroll
    for (int p = 0; p < 2; ++p) {
        float s = 0.0f;
#pragma unroll
        for (int z = 0; z < ZD; ++z) s += bev[p * 8 + z];
        tmp[(2 * wid2 + p) * ED + lane] = s * 0.125f;
    }
}

// tmp (Y*X, E) -> out (E, Y*X) via LDS tile transpose (fully coalesced both ways)
__global__ __launch_bounds__(256) void k_transpose(const float* __restrict__ tmp,
                                                   float* __restrict__ out) {
    __shared__ float tile[64][65];
    const int p0 = blockIdx.x * 64;
    const int lane = threadIdx.x & 63;
    const int r = threadIdx.x >> 6;
#pragma unroll
    for (int i = 0; i < 16; ++i) {
        int row = r + 4 * i;
        tile[row][lane] = tmp[(p0 + row) * ED + lane];
    }
    __syncthreads();
#pragma unroll
    for (int i = 0; i < 16; ++i) {
        int erow = r + 4 * i;
        out[erow * (YD * XD) + p0 + lane] = tile[lane][erow];
    }
}

extern "C" void kernel_launch(void* const* d_in, const int* in_sizes, int n_in,
                              void* d_out, int out_size, void* d_ws, size_t ws_size,
                              hipStream_t stream) {
    const float* Tv      = (const float*)d_in[0];
    const float* intr    = (const float*)d_in[1];
    const float* img     = (const float*)d_in[2];
    const float* bev_in  = (const float*)d_in[3];
    const float* W_off   = (const float*)d_in[4];
    const float* b_off   = (const float*)d_in[5];
    const float* s_off   = (const float*)d_in[6];
    const float* W_w     = (const float*)d_in[7];
    const float* b_w     = (const float*)d_in[8];
    const float* W_l     = (const float*)d_in[9];
    const float* b_l     = (const float*)d_in[10];
    const float* ln_g    = (const float*)d_in[11];
    const float* ln_b    = (const float*)d_in[12];
    float* out = (float*)d_out;

    char* ws = (char*)d_ws;
    unsigned* imgP = (unsigned*)ws;                            // 7,864,320 B
    float* tmp = (float*)(ws + 7864320);                       // 4,194,304 B
    unsigned short* W9f = (unsigned short*)(ws + 7864320 + 4194304);        // 6,144 B
    unsigned short* Wlf = (unsigned short*)(ws + 7864320 + 4194304 + 6144); // 24,576 B

    // prep: paired-column bf16 image (480 blocks) + weight frags (8 blocks)
    k_prep<<<(FHD * FWD) / 64 + 8, 256, 0, stream>>>(img, imgP, W_off, W_w, W_l,
                                                     W9f, Wlf);
    // main fused loop: 8192 waves, 2 points each; coalesced tmp writes
    k_main<<<(XD * YD / 2) / 4, 256, 0, stream>>>(Tv, intr, imgP, bev_in,
                                                  W9f, Wlf, b_off, s_off, b_w,
                                                  b_l, ln_g, ln_b, tmp);
    // transpose (Y*X,E) -> (E,Y*X)
    k_transpose<<<(YD * XD) / 64, 256, 0, stream>>>(tmp, out);
}